// Round 13
// baseline (2934.864 us; speedup 1.0000x reference)
//
#include <hip/hip_runtime.h>

// ---------- types / helpers ----------
typedef __attribute__((ext_vector_type(8))) short bf16x8;   // 8 bf16 (4 VGPRs)
typedef __attribute__((ext_vector_type(4))) float f32x4;    // MFMA accumulator

#define GLOAD_LDS16(g, l)                                                     \
  __builtin_amdgcn_global_load_lds(                                           \
      (const __attribute__((address_space(1))) void*)(g),                     \
      (__attribute__((address_space(3))) void*)(l), 16, 0, 0)

#define ALOAD64(p)  __hip_atomic_load((p), __ATOMIC_RELAXED, __HIP_MEMORY_SCOPE_AGENT)
#define ALOADU32(p) __hip_atomic_load((p), __ATOMIC_RELAXED, __HIP_MEMORY_SCOPE_AGENT)
#define ASTOREU32(p, v) __hip_atomic_store((p), (v), __ATOMIC_RELAXED, __HIP_MEMORY_SCOPE_AGENT)

__device__ __forceinline__ unsigned short f2b(float f) {
  union { float f; unsigned int i; } v; v.f = f;
  unsigned int u = v.i;
  u += 0x7fffu + ((u >> 16) & 1u);   // RNE
  return (unsigned short)(u >> 16);
}
__device__ __forceinline__ float sigm(float x) { return 1.f / (1.f + expf(-x)); }

// Problem constants
#define HH   1024
#define H3   3072
#define BB   8
#define SP   384     // padded sequence (383 real + 1 pad)
#define SL   383
#define VV   32000
#define II   512
#define MQ   2048    // B*T rows for attention tail

// TAG(step) = step+1 (flags zeroed in-graph each replay; 0 never matches)
#define TAG(s) ((unsigned)((s) + 1))

// ---------- fused fp32 -> bf16 convert of all 6 weight mats (contiguous dst) ----------
#define CB0 393216     // Wih0  3072x512
#define CB1 1179648    // Whh0  3072x1024
#define CB2 1966080    // Wih1  3072x1024
#define CB3 2752512    // Whh1  3072x1024
#define CB4 3276800    // Wc    1024x2048
#define CB5 11468800   // Wv    32000x1024
__global__ void k_cvt_all(const float* __restrict__ s0, const float* __restrict__ s1,
                          const float* __restrict__ s2, const float* __restrict__ s3,
                          const float* __restrict__ s4, const float* __restrict__ s5,
                          unsigned short* __restrict__ dst) {
  for (int i = blockIdx.x * 256 + threadIdx.x; i < CB5; i += 2048 * 256) {
    const float* src; int o;
    if (i < CB0)      { src = s0; o = i; }
    else if (i < CB1) { src = s1; o = i - CB0; }
    else if (i < CB2) { src = s2; o = i - CB1; }
    else if (i < CB3) { src = s3; o = i - CB2; }
    else if (i < CB4) { src = s4; o = i - CB3; }
    else              { src = s5; o = i - CB4; }
    float4 v = ((const float4*)src)[o];
    ushort4 q;
    q.x = f2b(v.x); q.y = f2b(v.y); q.z = f2b(v.z); q.w = f2b(v.w);
    ((ushort4*)dst)[i] = q;
  }
}

// ---------- zero u32 ----------
__global__ void k_zero_u32(unsigned int* p, int n) {
  int i = blockIdx.x * 256 + threadIdx.x;
  if (i < n) p[i] = 0u;
}

// ---------- embedding gather -> bf16, layout m = b*384 + s ----------
__global__ void k_embed(const int* __restrict__ input, const int* __restrict__ targets,
                        const float* __restrict__ embed_w, unsigned short* __restrict__ emb) {
  int m = blockIdx.x;              // 0..3071
  int b = m / SP, s = m % SP;
  unsigned short* dst = emb + (size_t)m * II;
  if (s == SL) {                   // pad row
    for (int i = threadIdx.x; i < II; i += 256) dst[i] = 0;
    return;
  }
  int tok = (s < 128) ? input[b * 128 + s] : targets[b * 256 + (s - 128)];
  const float* srcw = embed_w + (size_t)tok * II;
  for (int i = threadIdx.x; i < II; i += 256) dst[i] = f2b(srcw[i]);
}

// ---------- 2-phase double-buffered bf16 GEMM: C = A@W^T + bias ----------
template<bool TANH, bool OUTBF16>
__global__ __launch_bounds__(256) void k_gemm_bt(
    const unsigned short* __restrict__ A, const unsigned short* __restrict__ W,
    const float* __restrict__ bias, void* __restrict__ Cout,
    int M, int N, int K) {
  __shared__ __align__(16) unsigned short As[2][128 * 32];
  __shared__ __align__(16) unsigned short Ws[2][128 * 32];
  const int tid = threadIdx.x;
  const int gx = gridDim.x;
  const int nwg = gx * gridDim.y;
  int orig = blockIdx.y * gx + blockIdx.x;
  int wg = ((nwg & 7) == 0) ? ((orig & 7) * (nwg >> 3) + (orig >> 3)) : orig;
  const int mBase = (wg / gx) * 128, nBase = (wg % gx) * 128;
  const int wid = tid >> 6, lane = tid & 63;
  const int wr = wid >> 1, wc = wid & 1;
  f32x4 acc[4][4];
#pragma unroll
  for (int i = 0; i < 4; ++i)
#pragma unroll
    for (int j = 0; j < 4; ++j) acc[i][j] = (f32x4){0.f, 0.f, 0.f, 0.f};

  const int r0 = tid >> 2, c0 = (tid & 3) * 8;
  const int kq8 = (lane >> 4) * 8;

  auto stage = [&](int kt, int b) {
#pragma unroll
    for (int pass = 0; pass < 2; ++pass) {
      int r = pass * 64 + r0;
      GLOAD_LDS16(A + (size_t)(mBase + r) * K + kt + c0, &As[b][r * 32 + c0]);
      GLOAD_LDS16(W + (size_t)(nBase + r) * K + kt + c0, &Ws[b][r * 32 + c0]);
    }
  };

  stage(0, 0);
  int cur = 0;
  for (int kt = 0; kt < K; kt += 32) {
    asm volatile("s_waitcnt vmcnt(0)" ::: "memory");
    __syncthreads();
    if (kt + 32 < K) stage(kt + 32, cur ^ 1);
    bf16x8 af[4], bfr[4];
#pragma unroll
    for (int mf = 0; mf < 4; ++mf)
      af[mf] = *(const bf16x8*)&As[cur][(wr * 64 + mf * 16 + (lane & 15)) * 32 + kq8];
#pragma unroll
    for (int nf = 0; nf < 4; ++nf)
      bfr[nf] = *(const bf16x8*)&Ws[cur][(wc * 64 + nf * 16 + (lane & 15)) * 32 + kq8];
#pragma unroll
    for (int mf = 0; mf < 4; ++mf)
#pragma unroll
      for (int nf = 0; nf < 4; ++nf)
        acc[mf][nf] = __builtin_amdgcn_mfma_f32_16x16x32_bf16(af[mf], bfr[nf], acc[mf][nf], 0, 0, 0);
    cur ^= 1;
  }
  const int rq = (lane >> 4) * 4;
#pragma unroll
  for (int mf = 0; mf < 4; ++mf) {
#pragma unroll
    for (int nf = 0; nf < 4; ++nf) {
      int n = nBase + wc * 64 + nf * 16 + (lane & 15);
      float bvv = bias[n];
#pragma unroll
      for (int i = 0; i < 4; ++i) {
        int m = mBase + wr * 64 + mf * 16 + rq + i;
        float v = acc[mf][nf][i] + bvv;
        if (TANH) v = tanhf(v);
        if (OUTBF16) ((unsigned short*)Cout)[(size_t)m * N + n] = f2b(v);
        else         ((float*)Cout)[(size_t)m * N + n] = v;
      }
    }
  }
}

// ---------- O fp32 -> Obf bf16 + ObfT bf16 (transposed) + Q rows into X ----------
// grid (32, 12, 8) block 256 (32x8).
__global__ __launch_bounds__(256) void k_obf(const float* __restrict__ O,
                                             unsigned short* __restrict__ Obf,
                                             unsigned short* __restrict__ ObfT,
                                             unsigned short* __restrict__ X) {
  __shared__ unsigned short t[32][33];
  const int b = blockIdx.z, k0 = blockIdx.y * 32, h0 = blockIdx.x * 32;
  const int tx = threadIdx.x & 31, ty = threadIdx.x >> 5;   // 32 x 8
  const float* Ob = O + ((size_t)b * SP + k0) * 1024 + h0;
#pragma unroll
  for (int i = 0; i < 32; i += 8) {
    int krow = k0 + ty + i;
    unsigned short q = f2b(Ob[(size_t)(ty + i) * 1024 + tx]);
    Obf[((size_t)b * SP + krow) * 1024 + h0 + tx] = q;
    if (krow >= 127 && krow < 383)
      X[((size_t)(b * 256 + krow - 127)) * 2048 + h0 + tx] = q;
    t[ty + i][tx] = q;
  }
  __syncthreads();
#pragma unroll
  for (int i = 0; i < 32; i += 8)
    ObfT[((size_t)b * 1024 + h0 + ty + i) * SP + k0 + tx] = t[tx][ty + i];
}

// ---------- S = Q @ O^T per batch (MFMA, fp32 out), grid (3, 2, 8) ----------
__global__ __launch_bounds__(256) void k_gemm_qk(
    const unsigned short* __restrict__ Obf, float* __restrict__ Sout) {
  const int b = blockIdx.z;
  const unsigned short* A = Obf + (size_t)b * 393216 + 127 * 1024;  // Q: 256 x 1024
  const unsigned short* W = Obf + (size_t)b * 393216;               // keys: 384 x 1024
  float* Cout = Sout + (size_t)b * 98304;                           // 256 x 384
  const int K = 1024, N = 384;
  __shared__ __align__(16) unsigned short As[2][128 * 32];
  __shared__ __align__(16) unsigned short Ws[2][128 * 32];
  const int tid = threadIdx.x;
  const int mBase = blockIdx.y * 128, nBase = blockIdx.x * 128;
  const int wid = tid >> 6, lane = tid & 63;
  const int wr = wid >> 1, wc = wid & 1;
  f32x4 acc[4][4];
#pragma unroll
  for (int i = 0; i < 4; ++i)
#pragma unroll
    for (int j = 0; j < 4; ++j) acc[i][j] = (f32x4){0.f, 0.f, 0.f, 0.f};
  const int r0 = tid >> 2, c0 = (tid & 3) * 8;
  const int kq8 = (lane >> 4) * 8;
  auto stage = [&](int kt, int bb) {
#pragma unroll
    for (int pass = 0; pass < 2; ++pass) {
      int r = pass * 64 + r0;
      GLOAD_LDS16(A + (size_t)(mBase + r) * K + kt + c0, &As[bb][r * 32 + c0]);
      GLOAD_LDS16(W + (size_t)(nBase + r) * K + kt + c0, &Ws[bb][r * 32 + c0]);
    }
  };
  stage(0, 0);
  int cur = 0;
  for (int kt = 0; kt < K; kt += 32) {
    asm volatile("s_waitcnt vmcnt(0)" ::: "memory");
    __syncthreads();
    if (kt + 32 < K) stage(kt + 32, cur ^ 1);
    bf16x8 af[4], bfr[4];
#pragma unroll
    for (int mf = 0; mf < 4; ++mf)
      af[mf] = *(const bf16x8*)&As[cur][(wr * 64 + mf * 16 + (lane & 15)) * 32 + kq8];
#pragma unroll
    for (int nf = 0; nf < 4; ++nf)
      bfr[nf] = *(const bf16x8*)&Ws[cur][(wc * 64 + nf * 16 + (lane & 15)) * 32 + kq8];
#pragma unroll
    for (int mf = 0; mf < 4; ++mf)
#pragma unroll
      for (int nf = 0; nf < 4; ++nf)
        acc[mf][nf] = __builtin_amdgcn_mfma_f32_16x16x32_bf16(af[mf], bfr[nf], acc[mf][nf], 0, 0, 0);
    cur ^= 1;
  }
  const int rq = (lane >> 4) * 4;
#pragma unroll
  for (int mf = 0; mf < 4; ++mf)
#pragma unroll
    for (int nf = 0; nf < 4; ++nf) {
      int n = nBase + wc * 64 + nf * 16 + (lane & 15);
#pragma unroll
      for (int i = 0; i < 4; ++i) {
        int m = mBase + wr * 64 + mf * 16 + rq + i;
        Cout[(size_t)m * N + n] = acc[mf][nf][i];
      }
    }
}

// ---------- masked softmax: S fp32 -> P bf16 (masked cols = 0), 1 wave/row ----------
__global__ __launch_bounds__(64) void k_sm(const float* __restrict__ S,
                                           unsigned short* __restrict__ P) {
  const int row = blockIdx.x;      // 0..2047
  const int q = row & 255;
  const int lim = 127 + q;         // valid k < lim
  const float* Sr = S + (size_t)row * SP;
  unsigned short* Pr = P + (size_t)row * SP;
  const int lane = threadIdx.x;
  float v[6];
  float mx = -INFINITY;
#pragma unroll
  for (int i = 0; i < 6; ++i) {
    int k = lane + i * 64;
    float x = (k < lim) ? Sr[k] : -INFINITY;
    v[i] = x; mx = fmaxf(mx, x);
  }
#pragma unroll
  for (int m = 1; m < 64; m <<= 1) mx = fmaxf(mx, __shfl_xor(mx, m));
  float sum = 0.f;
#pragma unroll
  for (int i = 0; i < 6; ++i) {
    float e = (v[i] == -INFINITY) ? 0.f : expf(v[i] - mx);
    v[i] = e; sum += e;
  }
#pragma unroll
  for (int m = 1; m < 64; m <<= 1) sum += __shfl_xor(sum, m);
  float rinv = 1.f / sum;
#pragma unroll
  for (int i = 0; i < 6; ++i) Pr[lane + i * 64] = f2b(v[i] * rinv);
}

// ---------- ctx = P @ O per batch (MFMA via ObfT), out -> X right half ----------
// grid (8, 2, 8). ldc = 2048.
__global__ __launch_bounds__(256) void k_gemm_pv(
    const unsigned short* __restrict__ Pbf, const unsigned short* __restrict__ ObfT,
    unsigned short* __restrict__ X) {
  const int b = blockIdx.z;
  const unsigned short* A = Pbf + (size_t)b * 98304;     // 256 x 384
  const unsigned short* W = ObfT + (size_t)b * 393216;   // 1024 x 384
  unsigned short* Cout = X + (size_t)(b * 256) * 2048 + 1024;
  const int K = SP, N = 1024;
  __shared__ __align__(16) unsigned short As[2][128 * 32];
  __shared__ __align__(16) unsigned short Ws[2][128 * 32];
  const int tid = threadIdx.x;
  const int mBase = blockIdx.y * 128, nBase = blockIdx.x * 128;
  const int wid = tid >> 6, lane = tid & 63;
  const int wr = wid >> 1, wc = wid & 1;
  f32x4 acc[4][4];
#pragma unroll
  for (int i = 0; i < 4; ++i)
#pragma unroll
    for (int j = 0; j < 4; ++j) acc[i][j] = (f32x4){0.f, 0.f, 0.f, 0.f};
  const int r0 = tid >> 2, c0 = (tid & 3) * 8;
  const int kq8 = (lane >> 4) * 8;
  auto stage = [&](int kt, int bb) {
#pragma unroll
    for (int pass = 0; pass < 2; ++pass) {
      int r = pass * 64 + r0;
      GLOAD_LDS16(A + (size_t)(mBase + r) * K + kt + c0, &As[bb][r * 32 + c0]);
      GLOAD_LDS16(W + (size_t)(nBase + r) * K + kt + c0, &Ws[bb][r * 32 + c0]);
    }
  };
  stage(0, 0);
  int cur = 0;
  for (int kt = 0; kt < K; kt += 32) {
    asm volatile("s_waitcnt vmcnt(0)" ::: "memory");
    __syncthreads();
    if (kt + 32 < K) stage(kt + 32, cur ^ 1);
    bf16x8 af[4], bfr[4];
#pragma unroll
    for (int mf = 0; mf < 4; ++mf)
      af[mf] = *(const bf16x8*)&As[cur][(wr * 64 + mf * 16 + (lane & 15)) * 32 + kq8];
#pragma unroll
    for (int nf = 0; nf < 4; ++nf)
      bfr[nf] = *(const bf16x8*)&Ws[cur][(wc * 64 + nf * 16 + (lane & 15)) * 32 + kq8];
#pragma unroll
    for (int mf = 0; mf < 4; ++mf)
#pragma unroll
      for (int nf = 0; nf < 4; ++nf)
        acc[mf][nf] = __builtin_amdgcn_mfma_f32_16x16x32_bf16(af[mf], bfr[nf], acc[mf][nf], 0, 0, 0);
    cur ^= 1;
  }
  const int rq = (lane >> 4) * 4;
#pragma unroll
  for (int mf = 0; mf < 4; ++mf)
#pragma unroll
    for (int nf = 0; nf < 4; ++nf) {
      int n = nBase + wc * 64 + nf * 16 + (lane & 15);
#pragma unroll
      for (int i = 0; i < 4; ++i) {
        int m = mBase + wr * 64 + mf * 16 + rq + i;
        Cout[(size_t)m * 2048 + n] = f2b(acc[mf][nf][i]);
      }
    }
}

// ---------- persistent cooperative GRU recurrence ----------
// r10/r12 protocol with two changes (no sync-semantics change):
//  (a) FULL-LENGTH rings (384 slots, never reused) -> rflag/WAR machinery
//      deleted entirely; flags are full-length too.
//  (b) COALESCED gate-thread map: 16 (L0) / 8 (L1) consecutive lanes write
//      consecutive u16 -> h stores are 32B/16B transactions, not 2B scatter;
//      store-drain (vmcnt0) shortens. Obuf/gi0 accesses coalesce too.
__global__ __launch_bounds__(256) void k_recur(
    const unsigned short* __restrict__ whh0, const unsigned short* __restrict__ wih1,
    const unsigned short* __restrict__ whh1,
    const float* __restrict__ gi0,
    const float* __restrict__ bhh0, const float* __restrict__ bih1,
    const float* __restrict__ bhh1,
    unsigned short* __restrict__ h1g, unsigned short* __restrict__ h2g,
    float* __restrict__ Obuf, unsigned* cnt) {
  extern __shared__ unsigned char smem[];
  unsigned short* wlds  = (unsigned short*)smem;
  unsigned short* hA    = (unsigned short*)(smem + 98304);
  unsigned short* hB    = (unsigned short*)(smem + 114688);
  unsigned short* zrow  = (unsigned short*)(smem + 131072);
  float*          gacc  = (float*)(smem + 133120);

  unsigned* pflag1 = cnt;            // [384][64]
  unsigned* pflag2 = cnt + 384 * 64; // [384][128]

  const int g = blockIdx.x, tid = threadIdx.x;
  const int layer = (g >= 64) ? 1 : 0;
  const int j0 = layer ? (g - 64) * 8 : g * 16;

  for (int p = 0; p < 24; ++p) {
    int c = p * 256 + tid;
    int rr = c >> 7;
    int co = (c & 127) * 8;
    int cs = co ^ ((rr & 7) * 8);
    const unsigned short* src;
    if (layer == 0) {
      int grow = (rr >> 4) * 1024 + j0 + (rr & 15);
      src = whh0 + (size_t)grow * 1024 + cs;
    } else {
      const unsigned short* base; int grow;
      if (rr < 16)      { base = wih1; grow = (rr < 8) ? (j0 + rr) : (1024 + j0 + rr - 8); }
      else if (rr < 32) { base = whh1; int r2 = rr - 16; grow = (r2 < 8) ? (j0 + r2) : (1024 + j0 + r2 - 8); }
      else if (rr < 40) { base = wih1; grow = 2048 + j0 + (rr - 32); }
      else              { base = whh1; grow = 2048 + j0 + (rr - 40); }
      src = base + (size_t)grow * 1024 + cs;
    }
    GLOAD_LDS16(src, wlds + (size_t)rr * 1024 + co);
  }
  {
    ((unsigned int*)zrow)[tid]       = 0u;
    ((unsigned int*)zrow)[tid + 256] = 0u;
    for (int i = tid; i < 1024; i += 256) gacc[i] = 0.f;
  }
  __syncthreads();

  const int w = tid >> 6, lane = tid & 63;
  const int arow = lane & 15, kq8 = (lane >> 4) * 8, bb = lane & 15;

  // hoisted gate constants + running state (COALESCED maps)
  float c0r = 0.f, c0z = 0.f, c0n = 0.f;
  float c1ir = 0.f, c1iz = 0.f, c1in = 0.f, c1hr = 0.f, c1hz = 0.f, c1hn = 0.f;
  float hprev = 0.f;
  if (layer == 0) {
    if (tid < 128) { int j = j0 + (tid & 15);   // b = tid>>4, cc = tid&15
      c0r = bhh0[j]; c0z = bhh0[1024 + j]; c0n = bhh0[2048 + j]; }
  } else {
    if (tid < 64)  { int j = j0 + (tid & 7);    // b = tid>>3, cc = tid&7
      c1ir = bih1[j]; c1iz = bih1[1024 + j]; c1in = bih1[2048 + j];
      c1hr = bhh1[j]; c1hz = bhh1[1024 + j]; c1hn = bhh1[2048 + j]; }
  }

  bool wact; int tb, nrows; int hsel;
  if (layer == 0) { wact = (w < 3); tb = w * 16; nrows = 16; hsel = 0; }
  else { wact = true; tb = (w < 2) ? w * 16 : (32 + (w - 2) * 8); nrows = (w < 2) ? 16 : 8;
         hsel = (w & 1); }
  const unsigned short* abase; int ax;
  if (arow < nrows) { abase = wlds + (size_t)(tb + arow) * 1024; ax = (arow & 7) * 8; }
  else              { abase = zrow; ax = 0; }
  const unsigned short* bbase0; int bx;
  {
    const unsigned short* hX = hsel ? hB : hA;
    if (bb < 8) { bbase0 = hX + (size_t)bb * 1024; bx = (bb & 7) * 8; }
    else        { bbase0 = zrow; bx = 0; }
  }
  const int rq = (lane >> 4) * 4;
  const int kbase = w * 512 + lane;

  for (int s = 0; s < 384; ++s) {
    const bool act = layer ? (s >= 1) : (s <= 382);
    const unsigned short* h1r = h1g + (size_t)(s - 1) * 8192;   // valid when s>=1
    const unsigned short* h2r = h2g + (size_t)(s - 2) * 8192;   // valid when s>=2
    unsigned short* h1w = h1g + (size_t)s * 8192;
    unsigned short* h2w = h2g + (size_t)(s - 1) * 8192;

    // 0) gi0 prefetch (coalesced map: b = tid>>4, j = j0 + (tid&15))
    float pr = 0.f, pz = 0.f, pn = 0.f;
    if (layer == 0 && act && tid < 128) {
      int b = tid >> 4, j = j0 + (tid & 15);
      size_t m3 = ((size_t)b * SP + s) * H3;
      pr = gi0[m3 + j]; pz = gi0[m3 + 1024 + j]; pn = gi0[m3 + 2048 + j];
    }

    // 1) arrival poll (wave 0, coalesced flag vector, no RMW)
    if (w == 0 && act && s >= 1) {
      const unsigned t = TAG(s - 1);
      const bool need2 = (layer == 1) && (s >= 2);
      unsigned* f1 = pflag1 + (s - 1) * 64;
      unsigned* f2 = pflag2 + (s - 1) * 128;
      for (int it = 0; it < 200000; ++it) {
        int ok = (ALOADU32(f1 + lane) == t);
        if (need2) {
          ok &= (ALOADU32(f2 + lane) == t);
          ok &= (ALOADU32(f2 + 64 + lane) == t);
        }
        if (__all(ok)) break;                 // bounded: loud fail, not a hang
        __builtin_amdgcn_s_sleep(1);
      }
    }
    __syncthreads();   // flags confirmed for whole WG before payload reads

    // 2) coalesced payload staging into LDS (post-flag => data valid)
    if (act && s >= 1) {
      const unsigned long long* p1 = (const unsigned long long*)h1r;
#pragma unroll
      for (int i = 0; i < 8; ++i) {
        int k = kbase + i * 64;
        unsigned long long v = ALOAD64(p1 + k);
        int b = k >> 8, e = (k & 255) * 4;
        *(unsigned long long*)(hA + b * 1024 + (e ^ (b * 8))) = v;
      }
      if ((layer == 1) && (s >= 2)) {
        const unsigned long long* p2 = (const unsigned long long*)h2r;
#pragma unroll
        for (int i = 0; i < 8; ++i) {
          int k = kbase + i * 64;
          unsigned long long v = ALOAD64(p2 + k);
          int b = k >> 8, e = (k & 255) * 4;
          *(unsigned long long*)(hB + b * 1024 + (e ^ (b * 8))) = v;
        }
      }
    }
    __syncthreads();

    // 3) MFMA from LDS
    bool domfma = act && wact && (layer == 0 ? (s >= 1) : (hsel == 0 ? (s >= 1) : (s >= 2)));
    if (domfma) {
      f32x4 a0 = (f32x4){0.f, 0.f, 0.f, 0.f};
      f32x4 a1 = (f32x4){0.f, 0.f, 0.f, 0.f};
#pragma unroll
      for (int kt = 0; kt < 32; kt += 2) {
        int ko0 = kt * 32 + kq8, ko1 = ko0 + 32;
        bf16x8 av0 = *(const bf16x8*)(abase + (ko0 ^ ax));
        bf16x8 hv0 = *(const bf16x8*)(bbase0 + (ko0 ^ bx));
        bf16x8 av1 = *(const bf16x8*)(abase + (ko1 ^ ax));
        bf16x8 hv1 = *(const bf16x8*)(bbase0 + (ko1 ^ bx));
        a0 = __builtin_amdgcn_mfma_f32_16x16x32_bf16(av0, hv0, a0, 0, 0, 0);
        a1 = __builtin_amdgcn_mfma_f32_16x16x32_bf16(av1, hv1, a1, 0, 0, 0);
      }
#pragma unroll
      for (int i = 0; i < 4; ++i)
        gacc[w * 256 + (rq + i) * 16 + (lane & 15)] = a0[i] + a1[i];
    }
    __syncthreads();

    // 4) gates (fp32) + COALESCED h stores + Obuf
    if (act) {
      if (layer == 0 && tid < 128) {
        int b = tid >> 4, cc = tid & 15; int j = j0 + cc;
        float gr = pr + gacc[cc * 16 + b]       + c0r;
        float gz = pz + gacc[256 + cc * 16 + b] + c0z;
        float hg =      gacc[512 + cc * 16 + b] + c0n;
        float r = sigm(gr), z = sigm(gz);
        float n = tanhf(pn + r * hg);
        float hn = (1.f - z) * n + z * hprev;
        hprev = hn;
        __hip_atomic_store(h1w + b * 1024 + j, f2b(hn),
                           __ATOMIC_RELAXED, __HIP_MEMORY_SCOPE_AGENT);
      } else if (layer == 1 && tid < 64) {
        int b = tid >> 3, cc = tid & 7; int j = j0 + cc;
        float gr = gacc[cc * 16 + b]       + c1ir + gacc[256 + cc * 16 + b]       + c1hr;
        float gz = gacc[(8 + cc) * 16 + b] + c1iz + gacc[256 + (8 + cc) * 16 + b] + c1hz;
        float gn = gacc[512 + cc * 16 + b] + c1in;
        float hg = gacc[768 + cc * 16 + b] + c1hn;
        float r = sigm(gr), z = sigm(gz);
        float n = tanhf(gn + r * hg);
        float hn = (1.f - z) * n + z * hprev;
        hprev = hn;
        __hip_atomic_store(h2w + b * 1024 + j, f2b(hn),
                           __ATOMIC_RELAXED, __HIP_MEMORY_SCOPE_AGENT);
        Obuf[((size_t)b * SP + (s - 1)) * 1024 + j] = hn;
      }
    }
    // 5) release: stores acked -> post own flag
    asm volatile("s_waitcnt vmcnt(0)" ::: "memory");
    __syncthreads();
    if (act && tid == 0) {
      if (layer == 0) ASTOREU32(pflag1 + s * 64 + g, TAG(s));
      else            ASTOREU32(pflag2 + s * 128 + (g - 64), TAG(s));
    }
  }
}

// ---------- host ----------
extern "C" void kernel_launch(void* const* d_in, const int* in_sizes, int n_in,
                              void* d_out, int out_size, void* d_ws, size_t ws_size,
                              hipStream_t stream) {
  (void)in_sizes; (void)n_in; (void)out_size; (void)ws_size;
  const int*   input   = (const int*)d_in[0];
  const int*   targets = (const int*)d_in[1];
  const float* embed_w = (const float*)d_in[2];
  const float* Wih0 = (const float*)d_in[3];
  const float* Whh0 = (const float*)d_in[4];
  const float* bih0 = (const float*)d_in[5];
  const float* bhh0 = (const float*)d_in[6];
  const float* Wih1 = (const float*)d_in[7];
  const float* Whh1 = (const float*)d_in[8];
  const float* bih1 = (const float*)d_in[9];
  const float* bhh1 = (const float*)d_in[10];
  const float* Wc   = (const float*)d_in[11];
  const float* bc   = (const float*)d_in[12];
  const float* Wv   = (const float*)d_in[13];
  const float* bv   = (const float*)d_in[14];
  float* out = (float*)d_out;

  char* ws = (char*)d_ws;
  size_t off = 0;
  auto alloc = [&](size_t bytes) {
    void* p = ws + off; off += (bytes + 255) & ~(size_t)255; return p;
  };
  unsigned short* Wih0b = (unsigned short*)alloc((size_t)H3 * II * 2);
  unsigned short* Whh0b = (unsigned short*)alloc((size_t)H3 * HH * 2);
  unsigned short* Wih1b = (unsigned short*)alloc((size_t)H3 * HH * 2);
  unsigned short* Whh1b = (unsigned short*)alloc((size_t)H3 * HH * 2);
  unsigned short* Wcb   = (unsigned short*)alloc((size_t)HH * 2048 * 2);
  unsigned short* Wvb   = (unsigned short*)alloc((size_t)VV * HH * 2);
  unsigned short* EMBb  = (unsigned short*)alloc((size_t)BB * SP * II * 2);
  float*          GI0   = (float*)alloc((size_t)BB * SP * H3 * 4);
  unsigned short* H1G   = (unsigned short*)alloc((size_t)384 * 8192 * 2);  // full-length ring
  unsigned short* H2G   = (unsigned short*)alloc((size_t)384 * 8192 * 2);  // full-length ring
  unsigned*       CNT   = (unsigned*)alloc((size_t)(384 * 64 + 384 * 128) * 4); // pflag1+pflag2
  float*          OBUF  = (float*)alloc((size_t)BB * SP * HH * 4);
  unsigned short* OBF   = (unsigned short*)alloc((size_t)BB * SP * HH * 2);
  unsigned short* OBFT  = (unsigned short*)alloc((size_t)BB * HH * SP * 2);
  float*          SBUF  = (float*)alloc((size_t)MQ * SP * 4);
  unsigned short* PBF   = (unsigned short*)alloc((size_t)MQ * SP * 2);
  unsigned short* Xb    = (unsigned short*)alloc((size_t)MQ * 2048 * 2);
  unsigned short* COMBb = (unsigned short*)alloc((size_t)MQ * HH * 2);

  // fused convert of all six weight matrices (one launch)
  k_cvt_all<<<dim3(2048), 256, 0, stream>>>(Wih0, Whh0, Wih1, Whh1, Wc, Wv, Wih0b);

  k_embed<<<dim3(BB * SP), 256, 0, stream>>>(input, targets, embed_w, EMBb);
  // zero flags (73728 u32) every replay
  k_zero_u32<<<dim3(288), 256, 0, stream>>>((unsigned int*)CNT, 73728);

  // gi0 = emb @ Wih0^T + bih0   (M=3072, N=3072, K=512), fp32 out
  k_gemm_bt<false, false><<<dim3(24, 24), 256, 0, stream>>>(
      EMBb, Wih0b, bih0, GI0, BB * SP, H3, II);

  // persistent pipelined recurrence
  {
    const unsigned short* a0 = Whh0b; const unsigned short* a1 = Wih1b;
    const unsigned short* a2 = Whh1b; const float* a3 = GI0;
    const float* a4 = bhh0; const float* a5 = bih1; const float* a6 = bhh1;
    unsigned short* a7 = H1G; unsigned short* a8 = H2G; float* a9 = OBUF;
    unsigned* a10 = CNT;
    void* args[] = {&a0, &a1, &a2, &a3, &a4, &a5, &a6, &a7, &a8, &a9, &a10};
    hipLaunchCooperativeKernel((void*)k_recur, dim3(192), dim3(256),
                               args, 137216u, stream);
  }

  // MFMA attention: O->bf16(+T, +Q rows into X), S=Q@O^T, softmax, ctx=P@O
  k_obf<<<dim3(32, 12, 8), 256, 0, stream>>>(OBUF, OBF, OBFT, Xb);
  k_gemm_qk<<<dim3(3, 2, 8), 256, 0, stream>>>(OBF, SBUF);
  k_sm<<<dim3(2048), 64, 0, stream>>>(SBUF, PBF);
  k_gemm_pv<<<dim3(8, 2, 8), 256, 0, stream>>>(PBF, OBFT, Xb);

  // comb = tanh(X @ Wc^T + bc)  (M=2048, N=1024, K=2048), bf16 out
  k_gemm_bt<true, true><<<dim3(8, 16), 256, 0, stream>>>(
      Xb, Wcb, bc, COMBb, MQ, HH, 2048);

  // logits = comb @ Wv^T + bv   (M=2048, N=32000, K=1024), fp32 -> d_out
  k_gemm_bt<false, false><<<dim3(250, 16), 256, 0, stream>>>(
      COMBb, Wvb, bv, out, MQ, VV, HH);
}

// Round 14
// 2780.939 us; speedup vs baseline: 1.0554x; 1.0554x over previous
//
#include <hip/hip_runtime.h>

// ---------- types / helpers ----------
typedef __attribute__((ext_vector_type(8))) short bf16x8;   // 8 bf16 (4 VGPRs)
typedef __attribute__((ext_vector_type(4))) float f32x4;    // MFMA accumulator

#define GLOAD_LDS16(g, l)                                                     \
  __builtin_amdgcn_global_load_lds(                                           \
      (const __attribute__((address_space(1))) void*)(g),                     \
      (__attribute__((address_space(3))) void*)(l), 16, 0, 0)

#define ALOAD64(p)  __hip_atomic_load((p), __ATOMIC_RELAXED, __HIP_MEMORY_SCOPE_AGENT)
#define ALOADU32(p) __hip_atomic_load((p), __ATOMIC_RELAXED, __HIP_MEMORY_SCOPE_AGENT)
#define ASTOREU32(p, v) __hip_atomic_store((p), (v), __ATOMIC_RELAXED, __HIP_MEMORY_SCOPE_AGENT)

__device__ __forceinline__ unsigned short f2b(float f) {
  union { float f; unsigned int i; } v; v.f = f;
  unsigned int u = v.i;
  u += 0x7fffu + ((u >> 16) & 1u);   // RNE
  return (unsigned short)(u >> 16);
}
__device__ __forceinline__ float sigm(float x) { return 1.f / (1.f + expf(-x)); }

// Problem constants
#define HH   1024
#define H3   3072
#define BB   8
#define SP   384     // padded sequence (383 real + 1 pad)
#define SL   383
#define VV   32000
#define II   512
#define MQ   2048    // B*T rows for attention tail

// TAG(step) = step+1 (flags zeroed in-graph each replay; 0 never matches)
#define TAG(s) ((unsigned)((s) + 1))

// ---------- fused fp32 -> bf16 convert of all 6 weight mats (contiguous dst) ----------
#define CB0 393216     // Wih0  3072x512
#define CB1 1179648    // Whh0  3072x1024
#define CB2 1966080    // Wih1  3072x1024
#define CB3 2752512    // Whh1  3072x1024
#define CB4 3276800    // Wc    1024x2048
#define CB5 11468800   // Wv    32000x1024
__global__ void k_cvt_all(const float* __restrict__ s0, const float* __restrict__ s1,
                          const float* __restrict__ s2, const float* __restrict__ s3,
                          const float* __restrict__ s4, const float* __restrict__ s5,
                          unsigned short* __restrict__ dst) {
  for (int i = blockIdx.x * 256 + threadIdx.x; i < CB5; i += 2048 * 256) {
    const float* src; int o;
    if (i < CB0)      { src = s0; o = i; }
    else if (i < CB1) { src = s1; o = i - CB0; }
    else if (i < CB2) { src = s2; o = i - CB1; }
    else if (i < CB3) { src = s3; o = i - CB2; }
    else if (i < CB4) { src = s4; o = i - CB3; }
    else              { src = s5; o = i - CB4; }
    float4 v = ((const float4*)src)[o];
    ushort4 q;
    q.x = f2b(v.x); q.y = f2b(v.y); q.z = f2b(v.z); q.w = f2b(v.w);
    ((ushort4*)dst)[i] = q;
  }
}

// ---------- zero u32 ----------
__global__ void k_zero_u32(unsigned int* p, int n) {
  int i = blockIdx.x * 256 + threadIdx.x;
  if (i < n) p[i] = 0u;
}

// ---------- embedding gather -> bf16, layout m = b*384 + s ----------
__global__ void k_embed(const int* __restrict__ input, const int* __restrict__ targets,
                        const float* __restrict__ embed_w, unsigned short* __restrict__ emb) {
  int m = blockIdx.x;              // 0..3071
  int b = m / SP, s = m % SP;
  unsigned short* dst = emb + (size_t)m * II;
  if (s == SL) {                   // pad row
    for (int i = threadIdx.x; i < II; i += 256) dst[i] = 0;
    return;
  }
  int tok = (s < 128) ? input[b * 128 + s] : targets[b * 256 + (s - 128)];
  const float* srcw = embed_w + (size_t)tok * II;
  for (int i = threadIdx.x; i < II; i += 256) dst[i] = f2b(srcw[i]);
}

// ---------- 2-phase double-buffered bf16 GEMM: C = A@W^T + bias ----------
template<bool TANH, bool OUTBF16>
__global__ __launch_bounds__(256) void k_gemm_bt(
    const unsigned short* __restrict__ A, const unsigned short* __restrict__ W,
    const float* __restrict__ bias, void* __restrict__ Cout,
    int M, int N, int K) {
  __shared__ __align__(16) unsigned short As[2][128 * 32];
  __shared__ __align__(16) unsigned short Ws[2][128 * 32];
  const int tid = threadIdx.x;
  const int gx = gridDim.x;
  const int nwg = gx * gridDim.y;
  int orig = blockIdx.y * gx + blockIdx.x;
  int wg = ((nwg & 7) == 0) ? ((orig & 7) * (nwg >> 3) + (orig >> 3)) : orig;
  const int mBase = (wg / gx) * 128, nBase = (wg % gx) * 128;
  const int wid = tid >> 6, lane = tid & 63;
  const int wr = wid >> 1, wc = wid & 1;
  f32x4 acc[4][4];
#pragma unroll
  for (int i = 0; i < 4; ++i)
#pragma unroll
    for (int j = 0; j < 4; ++j) acc[i][j] = (f32x4){0.f, 0.f, 0.f, 0.f};

  const int r0 = tid >> 2, c0 = (tid & 3) * 8;
  const int kq8 = (lane >> 4) * 8;

  auto stage = [&](int kt, int b) {
#pragma unroll
    for (int pass = 0; pass < 2; ++pass) {
      int r = pass * 64 + r0;
      GLOAD_LDS16(A + (size_t)(mBase + r) * K + kt + c0, &As[b][r * 32 + c0]);
      GLOAD_LDS16(W + (size_t)(nBase + r) * K + kt + c0, &Ws[b][r * 32 + c0]);
    }
  };

  stage(0, 0);
  int cur = 0;
  for (int kt = 0; kt < K; kt += 32) {
    asm volatile("s_waitcnt vmcnt(0)" ::: "memory");
    __syncthreads();
    if (kt + 32 < K) stage(kt + 32, cur ^ 1);
    bf16x8 af[4], bfr[4];
#pragma unroll
    for (int mf = 0; mf < 4; ++mf)
      af[mf] = *(const bf16x8*)&As[cur][(wr * 64 + mf * 16 + (lane & 15)) * 32 + kq8];
#pragma unroll
    for (int nf = 0; nf < 4; ++nf)
      bfr[nf] = *(const bf16x8*)&Ws[cur][(wc * 64 + nf * 16 + (lane & 15)) * 32 + kq8];
#pragma unroll
    for (int mf = 0; mf < 4; ++mf)
#pragma unroll
      for (int nf = 0; nf < 4; ++nf)
        acc[mf][nf] = __builtin_amdgcn_mfma_f32_16x16x32_bf16(af[mf], bfr[nf], acc[mf][nf], 0, 0, 0);
    cur ^= 1;
  }
  const int rq = (lane >> 4) * 4;
#pragma unroll
  for (int mf = 0; mf < 4; ++mf) {
#pragma unroll
    for (int nf = 0; nf < 4; ++nf) {
      int n = nBase + wc * 64 + nf * 16 + (lane & 15);
      float bvv = bias[n];
#pragma unroll
      for (int i = 0; i < 4; ++i) {
        int m = mBase + wr * 64 + mf * 16 + rq + i;
        float v = acc[mf][nf][i] + bvv;
        if (TANH) v = tanhf(v);
        if (OUTBF16) ((unsigned short*)Cout)[(size_t)m * N + n] = f2b(v);
        else         ((float*)Cout)[(size_t)m * N + n] = v;
      }
    }
  }
}

// ---------- O fp32 -> Obf bf16 + ObfT bf16 (transposed) + Q rows into X ----------
// grid (32, 12, 8) block 256 (32x8).
__global__ __launch_bounds__(256) void k_obf(const float* __restrict__ O,
                                             unsigned short* __restrict__ Obf,
                                             unsigned short* __restrict__ ObfT,
                                             unsigned short* __restrict__ X) {
  __shared__ unsigned short t[32][33];
  const int b = blockIdx.z, k0 = blockIdx.y * 32, h0 = blockIdx.x * 32;
  const int tx = threadIdx.x & 31, ty = threadIdx.x >> 5;   // 32 x 8
  const float* Ob = O + ((size_t)b * SP + k0) * 1024 + h0;
#pragma unroll
  for (int i = 0; i < 32; i += 8) {
    int krow = k0 + ty + i;
    unsigned short q = f2b(Ob[(size_t)(ty + i) * 1024 + tx]);
    Obf[((size_t)b * SP + krow) * 1024 + h0 + tx] = q;
    if (krow >= 127 && krow < 383)
      X[((size_t)(b * 256 + krow - 127)) * 2048 + h0 + tx] = q;
    t[ty + i][tx] = q;
  }
  __syncthreads();
#pragma unroll
  for (int i = 0; i < 32; i += 8)
    ObfT[((size_t)b * 1024 + h0 + ty + i) * SP + k0 + tx] = t[tx][ty + i];
}

// ---------- S = Q @ O^T per batch (MFMA, fp32 out), grid (3, 2, 8) ----------
__global__ __launch_bounds__(256) void k_gemm_qk(
    const unsigned short* __restrict__ Obf, float* __restrict__ Sout) {
  const int b = blockIdx.z;
  const unsigned short* A = Obf + (size_t)b * 393216 + 127 * 1024;  // Q: 256 x 1024
  const unsigned short* W = Obf + (size_t)b * 393216;               // keys: 384 x 1024
  float* Cout = Sout + (size_t)b * 98304;                           // 256 x 384
  const int K = 1024, N = 384;
  __shared__ __align__(16) unsigned short As[2][128 * 32];
  __shared__ __align__(16) unsigned short Ws[2][128 * 32];
  const int tid = threadIdx.x;
  const int mBase = blockIdx.y * 128, nBase = blockIdx.x * 128;
  const int wid = tid >> 6, lane = tid & 63;
  const int wr = wid >> 1, wc = wid & 1;
  f32x4 acc[4][4];
#pragma unroll
  for (int i = 0; i < 4; ++i)
#pragma unroll
    for (int j = 0; j < 4; ++j) acc[i][j] = (f32x4){0.f, 0.f, 0.f, 0.f};
  const int r0 = tid >> 2, c0 = (tid & 3) * 8;
  const int kq8 = (lane >> 4) * 8;
  auto stage = [&](int kt, int bb) {
#pragma unroll
    for (int pass = 0; pass < 2; ++pass) {
      int r = pass * 64 + r0;
      GLOAD_LDS16(A + (size_t)(mBase + r) * K + kt + c0, &As[bb][r * 32 + c0]);
      GLOAD_LDS16(W + (size_t)(nBase + r) * K + kt + c0, &Ws[bb][r * 32 + c0]);
    }
  };
  stage(0, 0);
  int cur = 0;
  for (int kt = 0; kt < K; kt += 32) {
    asm volatile("s_waitcnt vmcnt(0)" ::: "memory");
    __syncthreads();
    if (kt + 32 < K) stage(kt + 32, cur ^ 1);
    bf16x8 af[4], bfr[4];
#pragma unroll
    for (int mf = 0; mf < 4; ++mf)
      af[mf] = *(const bf16x8*)&As[cur][(wr * 64 + mf * 16 + (lane & 15)) * 32 + kq8];
#pragma unroll
    for (int nf = 0; nf < 4; ++nf)
      bfr[nf] = *(const bf16x8*)&Ws[cur][(wc * 64 + nf * 16 + (lane & 15)) * 32 + kq8];
#pragma unroll
    for (int mf = 0; mf < 4; ++mf)
#pragma unroll
      for (int nf = 0; nf < 4; ++nf)
        acc[mf][nf] = __builtin_amdgcn_mfma_f32_16x16x32_bf16(af[mf], bfr[nf], acc[mf][nf], 0, 0, 0);
    cur ^= 1;
  }
  const int rq = (lane >> 4) * 4;
#pragma unroll
  for (int mf = 0; mf < 4; ++mf)
#pragma unroll
    for (int nf = 0; nf < 4; ++nf) {
      int n = nBase + wc * 64 + nf * 16 + (lane & 15);
#pragma unroll
      for (int i = 0; i < 4; ++i) {
        int m = mBase + wr * 64 + mf * 16 + rq + i;
        Cout[(size_t)m * N + n] = acc[mf][nf][i];
      }
    }
}

// ---------- masked softmax: S fp32 -> P bf16 (masked cols = 0), 1 wave/row ----------
__global__ __launch_bounds__(64) void k_sm(const float* __restrict__ S,
                                           unsigned short* __restrict__ P) {
  const int row = blockIdx.x;      // 0..2047
  const int q = row & 255;
  const int lim = 127 + q;         // valid k < lim
  const float* Sr = S + (size_t)row * SP;
  unsigned short* Pr = P + (size_t)row * SP;
  const int lane = threadIdx.x;
  float v[6];
  float mx = -INFINITY;
#pragma unroll
  for (int i = 0; i < 6; ++i) {
    int k = lane + i * 64;
    float x = (k < lim) ? Sr[k] : -INFINITY;
    v[i] = x; mx = fmaxf(mx, x);
  }
#pragma unroll
  for (int m = 1; m < 64; m <<= 1) mx = fmaxf(mx, __shfl_xor(mx, m));
  float sum = 0.f;
#pragma unroll
  for (int i = 0; i < 6; ++i) {
    float e = (v[i] == -INFINITY) ? 0.f : expf(v[i] - mx);
    v[i] = e; sum += e;
  }
#pragma unroll
  for (int m = 1; m < 64; m <<= 1) sum += __shfl_xor(sum, m);
  float rinv = 1.f / sum;
#pragma unroll
  for (int i = 0; i < 6; ++i) Pr[lane + i * 64] = f2b(v[i] * rinv);
}

// ---------- ctx = P @ O per batch (MFMA via ObfT), out -> X right half ----------
// grid (8, 2, 8). ldc = 2048.
__global__ __launch_bounds__(256) void k_gemm_pv(
    const unsigned short* __restrict__ Pbf, const unsigned short* __restrict__ ObfT,
    unsigned short* __restrict__ X) {
  const int b = blockIdx.z;
  const unsigned short* A = Pbf + (size_t)b * 98304;     // 256 x 384
  const unsigned short* W = ObfT + (size_t)b * 393216;   // 1024 x 384
  unsigned short* Cout = X + (size_t)(b * 256) * 2048 + 1024;
  const int K = SP, N = 1024;
  __shared__ __align__(16) unsigned short As[2][128 * 32];
  __shared__ __align__(16) unsigned short Ws[2][128 * 32];
  const int tid = threadIdx.x;
  const int mBase = blockIdx.y * 128, nBase = blockIdx.x * 128;
  const int wid = tid >> 6, lane = tid & 63;
  const int wr = wid >> 1, wc = wid & 1;
  f32x4 acc[4][4];
#pragma unroll
  for (int i = 0; i < 4; ++i)
#pragma unroll
    for (int j = 0; j < 4; ++j) acc[i][j] = (f32x4){0.f, 0.f, 0.f, 0.f};
  const int r0 = tid >> 2, c0 = (tid & 3) * 8;
  const int kq8 = (lane >> 4) * 8;
  auto stage = [&](int kt, int bb) {
#pragma unroll
    for (int pass = 0; pass < 2; ++pass) {
      int r = pass * 64 + r0;
      GLOAD_LDS16(A + (size_t)(mBase + r) * K + kt + c0, &As[bb][r * 32 + c0]);
      GLOAD_LDS16(W + (size_t)(nBase + r) * K + kt + c0, &Ws[bb][r * 32 + c0]);
    }
  };
  stage(0, 0);
  int cur = 0;
  for (int kt = 0; kt < K; kt += 32) {
    asm volatile("s_waitcnt vmcnt(0)" ::: "memory");
    __syncthreads();
    if (kt + 32 < K) stage(kt + 32, cur ^ 1);
    bf16x8 af[4], bfr[4];
#pragma unroll
    for (int mf = 0; mf < 4; ++mf)
      af[mf] = *(const bf16x8*)&As[cur][(wr * 64 + mf * 16 + (lane & 15)) * 32 + kq8];
#pragma unroll
    for (int nf = 0; nf < 4; ++nf)
      bfr[nf] = *(const bf16x8*)&Ws[cur][(wc * 64 + nf * 16 + (lane & 15)) * 32 + kq8];
#pragma unroll
    for (int mf = 0; mf < 4; ++mf)
#pragma unroll
      for (int nf = 0; nf < 4; ++nf)
        acc[mf][nf] = __builtin_amdgcn_mfma_f32_16x16x32_bf16(af[mf], bfr[nf], acc[mf][nf], 0, 0, 0);
    cur ^= 1;
  }
  const int rq = (lane >> 4) * 4;
#pragma unroll
  for (int mf = 0; mf < 4; ++mf)
#pragma unroll
    for (int nf = 0; nf < 4; ++nf) {
      int n = nBase + wc * 64 + nf * 16 + (lane & 15);
#pragma unroll
      for (int i = 0; i < 4; ++i) {
        int m = mBase + wr * 64 + mf * 16 + rq + i;
        Cout[(size_t)m * 2048 + n] = f2b(acc[mf][nf][i]);
      }
    }
}

// ---------- persistent cooperative GRU recurrence (ROUND-12 VERBATIM) ----------
// Best-known config: 8-slot rings, pflag vectors + rflag WAR, r7 gate maps,
// coalesced u64 payload staging into XOR-swizzled LDS.
__global__ __launch_bounds__(256) void k_recur(
    const unsigned short* __restrict__ whh0, const unsigned short* __restrict__ wih1,
    const unsigned short* __restrict__ whh1,
    const float* __restrict__ gi0,
    const float* __restrict__ bhh0, const float* __restrict__ bih1,
    const float* __restrict__ bhh1,
    unsigned short* __restrict__ h1g, unsigned short* __restrict__ h2g,
    float* __restrict__ Obuf, unsigned* cnt) {
  extern __shared__ unsigned char smem[];
  unsigned short* wlds  = (unsigned short*)smem;
  unsigned short* hA    = (unsigned short*)(smem + 98304);
  unsigned short* hB    = (unsigned short*)(smem + 114688);
  unsigned short* zrow  = (unsigned short*)(smem + 131072);
  float*          gacc  = (float*)(smem + 133120);

  unsigned* pflag1 = cnt;
  unsigned* pflag2 = cnt + 512;
  unsigned* rflag  = cnt + 1536;

  const int g = blockIdx.x, tid = threadIdx.x;
  const int layer = (g >= 64) ? 1 : 0;
  const int j0 = layer ? (g - 64) * 8 : g * 16;

  for (int p = 0; p < 24; ++p) {
    int c = p * 256 + tid;
    int rr = c >> 7;
    int co = (c & 127) * 8;
    int cs = co ^ ((rr & 7) * 8);
    const unsigned short* src;
    if (layer == 0) {
      int grow = (rr >> 4) * 1024 + j0 + (rr & 15);
      src = whh0 + (size_t)grow * 1024 + cs;
    } else {
      const unsigned short* base; int grow;
      if (rr < 16)      { base = wih1; grow = (rr < 8) ? (j0 + rr) : (1024 + j0 + rr - 8); }
      else if (rr < 32) { base = whh1; int r2 = rr - 16; grow = (r2 < 8) ? (j0 + r2) : (1024 + j0 + r2 - 8); }
      else if (rr < 40) { base = wih1; grow = 2048 + j0 + (rr - 32); }
      else              { base = whh1; grow = 2048 + j0 + (rr - 40); }
      src = base + (size_t)grow * 1024 + cs;
    }
    GLOAD_LDS16(src, wlds + (size_t)rr * 1024 + co);
  }
  {
    ((unsigned int*)zrow)[tid]       = 0u;
    ((unsigned int*)zrow)[tid + 256] = 0u;
    for (int i = tid; i < 1024; i += 256) gacc[i] = 0.f;
  }
  __syncthreads();

  const int w = tid >> 6, lane = tid & 63;
  const int arow = lane & 15, kq8 = (lane >> 4) * 8, bb = lane & 15;

  float c0r = 0.f, c0z = 0.f, c0n = 0.f;
  float c1ir = 0.f, c1iz = 0.f, c1in = 0.f, c1hr = 0.f, c1hz = 0.f, c1hn = 0.f;
  float hprev = 0.f;
  if (layer == 0) {
    if (tid < 128) { int j = j0 + (tid >> 3); c0r = bhh0[j]; c0z = bhh0[1024 + j]; c0n = bhh0[2048 + j]; }
  } else {
    if (tid < 64)  { int j = j0 + (tid >> 3);
      c1ir = bih1[j]; c1iz = bih1[1024 + j]; c1in = bih1[2048 + j];
      c1hr = bhh1[j]; c1hz = bhh1[1024 + j]; c1hn = bhh1[2048 + j]; }
  }

  bool wact; int tb, nrows; int hsel;
  if (layer == 0) { wact = (w < 3); tb = w * 16; nrows = 16; hsel = 0; }
  else { wact = true; tb = (w < 2) ? w * 16 : (32 + (w - 2) * 8); nrows = (w < 2) ? 16 : 8;
         hsel = (w & 1); }
  const unsigned short* abase; int ax;
  if (arow < nrows) { abase = wlds + (size_t)(tb + arow) * 1024; ax = (arow & 7) * 8; }
  else              { abase = zrow; ax = 0; }
  const unsigned short* bbase0; int bx;
  {
    const unsigned short* hX = hsel ? hB : hA;
    if (bb < 8) { bbase0 = hX + (size_t)bb * 1024; bx = (bb & 7) * 8; }
    else        { bbase0 = zrow; bx = 0; }
  }
  const int rq = (lane >> 4) * 4;
  const int kbase = w * 512 + lane;

  for (int s = 0; s < 384; ++s) {
    const bool act = layer ? (s >= 1) : (s <= 382);
    const unsigned short* h1r = h1g + ((s - 1) & 7) * 8192;
    const unsigned short* h2r = h2g + ((s - 2) & 7) * 8192;
    unsigned short* h1w = h1g + (s & 7) * 8192;
    unsigned short* h2w = h2g + ((s - 1) & 7) * 8192;

    float pr = 0.f, pz = 0.f, pn = 0.f;
    if (layer == 0 && act && tid < 128) {
      int cc = tid >> 3, b = tid & 7; int j = j0 + cc;
      size_t m3 = ((size_t)b * SP + s) * H3;
      pr = gi0[m3 + j]; pz = gi0[m3 + 1024 + j]; pn = gi0[m3 + 2048 + j];
    }

    if (w == 0 && act && s >= 1) {
      const unsigned t = TAG(s - 1);
      const bool need2 = (layer == 1) && (s >= 2);
      unsigned* f1 = pflag1 + ((s - 1) & 7) * 64;
      unsigned* f2 = pflag2 + ((s - 1) & 7) * 128;
      for (int it = 0; it < 200000; ++it) {
        int ok = (ALOADU32(f1 + lane) == t);
        if (need2) {
          ok &= (ALOADU32(f2 + lane) == t);
          ok &= (ALOADU32(f2 + 64 + lane) == t);
        }
        if (__all(ok)) break;
        __builtin_amdgcn_s_sleep(1);
      }
    }
    if (w == 1 && (s & 3) == 0 && s >= 4) {
      const unsigned t = TAG(s - 4);
      unsigned* rf = rflag + ((s - 4) & 7) * 192;
      for (int it = 0; it < 100000; ++it) {
        int ok = (ALOADU32(rf + lane) == t)
               & (ALOADU32(rf + 64 + lane) == t)
               & (ALOADU32(rf + 128 + lane) == t);
        if (__all(ok)) break;
        __builtin_amdgcn_s_sleep(1);
      }
    }
    __syncthreads();

    if (act && s >= 1) {
      const unsigned long long* p1 = (const unsigned long long*)h1r;
#pragma unroll
      for (int i = 0; i < 8; ++i) {
        int k = kbase + i * 64;
        unsigned long long v = ALOAD64(p1 + k);
        int b = k >> 8, e = (k & 255) * 4;
        *(unsigned long long*)(hA + b * 1024 + (e ^ (b * 8))) = v;
      }
      if ((layer == 1) && (s >= 2)) {
        const unsigned long long* p2 = (const unsigned long long*)h2r;
#pragma unroll
        for (int i = 0; i < 8; ++i) {
          int k = kbase + i * 64;
          unsigned long long v = ALOAD64(p2 + k);
          int b = k >> 8, e = (k & 255) * 4;
          *(unsigned long long*)(hB + b * 1024 + (e ^ (b * 8))) = v;
        }
      }
    }
    __syncthreads();

    bool domfma = act && wact && (layer == 0 ? (s >= 1) : (hsel == 0 ? (s >= 1) : (s >= 2)));
    if (domfma) {
      f32x4 a0 = (f32x4){0.f, 0.f, 0.f, 0.f};
      f32x4 a1 = (f32x4){0.f, 0.f, 0.f, 0.f};
#pragma unroll
      for (int kt = 0; kt < 32; kt += 2) {
        int ko0 = kt * 32 + kq8, ko1 = ko0 + 32;
        bf16x8 av0 = *(const bf16x8*)(abase + (ko0 ^ ax));
        bf16x8 hv0 = *(const bf16x8*)(bbase0 + (ko0 ^ bx));
        bf16x8 av1 = *(const bf16x8*)(abase + (ko1 ^ ax));
        bf16x8 hv1 = *(const bf16x8*)(bbase0 + (ko1 ^ bx));
        a0 = __builtin_amdgcn_mfma_f32_16x16x32_bf16(av0, hv0, a0, 0, 0, 0);
        a1 = __builtin_amdgcn_mfma_f32_16x16x32_bf16(av1, hv1, a1, 0, 0, 0);
      }
#pragma unroll
      for (int i = 0; i < 4; ++i)
        gacc[w * 256 + (rq + i) * 16 + (lane & 15)] = a0[i] + a1[i];
    }
    __syncthreads();

    if (act) {
      if (layer == 0 && tid < 128) {
        int cc = tid >> 3, b = tid & 7; int j = j0 + cc;
        float gr = pr + gacc[cc * 16 + b]       + c0r;
        float gz = pz + gacc[256 + cc * 16 + b] + c0z;
        float hg =      gacc[512 + cc * 16 + b] + c0n;
        float r = sigm(gr), z = sigm(gz);
        float n = tanhf(pn + r * hg);
        float hn = (1.f - z) * n + z * hprev;
        hprev = hn;
        __hip_atomic_store(h1w + b * 1024 + j, f2b(hn),
                           __ATOMIC_RELAXED, __HIP_MEMORY_SCOPE_AGENT);
      } else if (layer == 1 && tid < 64) {
        int cc = tid >> 3, b = tid & 7; int j = j0 + cc;
        float gr = gacc[cc * 16 + b]       + c1ir + gacc[256 + cc * 16 + b]       + c1hr;
        float gz = gacc[(8 + cc) * 16 + b] + c1iz + gacc[256 + (8 + cc) * 16 + b] + c1hz;
        float gn = gacc[512 + cc * 16 + b] + c1in;
        float hg = gacc[768 + cc * 16 + b] + c1hn;
        float r = sigm(gr), z = sigm(gz);
        float n = tanhf(gn + r * hg);
        float hn = (1.f - z) * n + z * hprev;
        hprev = hn;
        __hip_atomic_store(h2w + b * 1024 + j, f2b(hn),
                           __ATOMIC_RELAXED, __HIP_MEMORY_SCOPE_AGENT);
        Obuf[((size_t)b * SP + (s - 1)) * 1024 + j] = hn;
      }
    }
    asm volatile("s_waitcnt vmcnt(0)" ::: "memory");
    __syncthreads();
    if (act && tid == 0) {
      if (layer == 0) ASTOREU32(pflag1 + (s & 7) * 64 + g, TAG(s));
      else            ASTOREU32(pflag2 + (s & 7) * 128 + (g - 64), TAG(s));
    }
    if (tid == 1) ASTOREU32(rflag + (s & 7) * 192 + g, TAG(s));
  }
}

// ---------- host ----------
extern "C" void kernel_launch(void* const* d_in, const int* in_sizes, int n_in,
                              void* d_out, int out_size, void* d_ws, size_t ws_size,
                              hipStream_t stream) {
  (void)in_sizes; (void)n_in; (void)out_size; (void)ws_size;
  const int*   input   = (const int*)d_in[0];
  const int*   targets = (const int*)d_in[1];
  const float* embed_w = (const float*)d_in[2];
  const float* Wih0 = (const float*)d_in[3];
  const float* Whh0 = (const float*)d_in[4];
  const float* bih0 = (const float*)d_in[5];
  const float* bhh0 = (const float*)d_in[6];
  const float* Wih1 = (const float*)d_in[7];
  const float* Whh1 = (const float*)d_in[8];
  const float* bih1 = (const float*)d_in[9];
  const float* bhh1 = (const float*)d_in[10];
  const float* Wc   = (const float*)d_in[11];
  const float* bc   = (const float*)d_in[12];
  const float* Wv   = (const float*)d_in[13];
  const float* bv   = (const float*)d_in[14];
  float* out = (float*)d_out;

  char* ws = (char*)d_ws;
  size_t off = 0;
  auto alloc = [&](size_t bytes) {
    void* p = ws + off; off += (bytes + 255) & ~(size_t)255; return p;
  };
  unsigned short* Wih0b = (unsigned short*)alloc((size_t)H3 * II * 2);
  unsigned short* Whh0b = (unsigned short*)alloc((size_t)H3 * HH * 2);
  unsigned short* Wih1b = (unsigned short*)alloc((size_t)H3 * HH * 2);
  unsigned short* Whh1b = (unsigned short*)alloc((size_t)H3 * HH * 2);
  unsigned short* Wcb   = (unsigned short*)alloc((size_t)HH * 2048 * 2);
  unsigned short* Wvb   = (unsigned short*)alloc((size_t)VV * HH * 2);
  unsigned short* EMBb  = (unsigned short*)alloc((size_t)BB * SP * II * 2);
  float*          GI0   = (float*)alloc((size_t)BB * SP * H3 * 4);
  unsigned short* H1G   = (unsigned short*)alloc(8 * 8192 * 2);   // 128KB ring
  unsigned short* H2G   = (unsigned short*)alloc(8 * 8192 * 2);   // 128KB ring
  unsigned*       CNT   = (unsigned*)alloc(3072 * 4);             // pflag1/2 + rflag
  float*          OBUF  = (float*)alloc((size_t)BB * SP * HH * 4);
  unsigned short* OBF   = (unsigned short*)alloc((size_t)BB * SP * HH * 2);
  unsigned short* OBFT  = (unsigned short*)alloc((size_t)BB * HH * SP * 2);
  float*          SBUF  = (float*)alloc((size_t)MQ * SP * 4);
  unsigned short* PBF   = (unsigned short*)alloc((size_t)MQ * SP * 2);
  unsigned short* Xb    = (unsigned short*)alloc((size_t)MQ * 2048 * 2);
  unsigned short* COMBb = (unsigned short*)alloc((size_t)MQ * HH * 2);

  // fused convert of all six weight matrices (one launch)
  k_cvt_all<<<dim3(2048), 256, 0, stream>>>(Wih0, Whh0, Wih1, Whh1, Wc, Wv, Wih0b);

  k_embed<<<dim3(BB * SP), 256, 0, stream>>>(input, targets, embed_w, EMBb);
  k_zero_u32<<<dim3(12), 256, 0, stream>>>((unsigned int*)CNT, 3072);

  // gi0 = emb @ Wih0^T + bih0   (M=3072, N=3072, K=512), fp32 out
  k_gemm_bt<false, false><<<dim3(24, 24), 256, 0, stream>>>(
      EMBb, Wih0b, bih0, GI0, BB * SP, H3, II);

  // persistent pipelined recurrence (r12 config)
  {
    const unsigned short* a0 = Whh0b; const unsigned short* a1 = Wih1b;
    const unsigned short* a2 = Whh1b; const float* a3 = GI0;
    const float* a4 = bhh0; const float* a5 = bih1; const float* a6 = bhh1;
    unsigned short* a7 = H1G; unsigned short* a8 = H2G; float* a9 = OBUF;
    unsigned* a10 = CNT;
    void* args[] = {&a0, &a1, &a2, &a3, &a4, &a5, &a6, &a7, &a8, &a9, &a10};
    hipLaunchCooperativeKernel((void*)k_recur, dim3(192), dim3(256),
                               args, 137216u, stream);
  }

  // MFMA attention: O->bf16(+T, +Q rows into X), S=Q@O^T, softmax, ctx=P@O
  k_obf<<<dim3(32, 12, 8), 256, 0, stream>>>(OBUF, OBF, OBFT, Xb);
  k_gemm_qk<<<dim3(3, 2, 8), 256, 0, stream>>>(OBF, SBUF);
  k_sm<<<dim3(2048), 64, 0, stream>>>(SBUF, PBF);
  k_gemm_pv<<<dim3(8, 2, 8), 256, 0, stream>>>(PBF, OBFT, Xb);

  // comb = tanh(X @ Wc^T + bc)  (M=2048, N=1024, K=2048), bf16 out
  k_gemm_bt<true, true><<<dim3(8, 16), 256, 0, stream>>>(
      Xb, Wcb, bc, COMBb, MQ, HH, 2048);

  // logits = comb @ Wv^T + bv   (M=2048, N=32000, K=1024), fp32 -> d_out
  k_gemm_bt<false, false><<<dim3(250, 16), 256, 0, stream>>>(
      COMBb, Wvb, bv, out, MQ, VV, HH);
}